// Round 1
// baseline (1225.105 us; speedup 1.0000x reference)
//
#include <hip/hip_runtime.h>
#include <cmath>

#define BB 8
#define CC 64
#define HH 128
#define WW 128

// ---------------------------------------------------------------------------
// Kernel A: feat = conv3x3(concat(x_vq, x_res), W1) + b1   -> NHWC [B,H,W,64]
// Tile 16x16 pixels, 2 oc-groups of 32, ic chunks of 16 staged in LDS.
// Weights read as wave-uniform scalar loads (index depends only on blockIdx +
// loop vars -> s_load path, co-issues with VALU FMAs).
// ---------------------------------------------------------------------------
__global__ __launch_bounds__(256)
void conv1_kernel(const float* __restrict__ xvq, const float* __restrict__ xres,
                  const float* __restrict__ W1, const float* __restrict__ b1,
                  float* __restrict__ feat)
{
    const int tx = threadIdx.x & 15;
    const int ty = threadIdx.x >> 4;
    const int x0 = blockIdx.x * 16;
    const int y0 = blockIdx.y * 16;
    const int b  = blockIdx.z >> 1;
    const int ocg = blockIdx.z & 1;

    __shared__ float sIn[16 * 18 * 19];   // [ic16][18 rows][19 stride] 21.9 KB

    float acc[32];
#pragma unroll
    for (int i = 0; i < 32; ++i) acc[i] = 0.f;

    for (int chunk = 0; chunk < 8; ++chunk) {
        const int icBase = chunk * 16;
        const float* src = (icBase < 64) ? xvq : xres;
        const int icOff = icBase & 63;
        __syncthreads();
        for (int idx = threadIdx.x; idx < 16 * 324; idx += 256) {
            const int ic = idx / 324;
            const int s  = idx - ic * 324;
            const int iy = s / 18;
            const int ix = s - iy * 18;
            const int gy = y0 + iy - 1;
            const int gx = x0 + ix - 1;
            float v = 0.f;
            if ((unsigned)gy < HH && (unsigned)gx < WW)
                v = src[(((size_t)b * CC + icOff + ic) * HH + gy) * WW + gx];
            sIn[(ic * 18 + iy) * 19 + ix] = v;
        }
        __syncthreads();
        const float* wbase = W1 + (size_t)(ocg * 32) * 1152 + icBase * 9;
        for (int ic = 0; ic < 16; ++ic) {
            float in[9];
#pragma unroll
            for (int dy = 0; dy < 3; ++dy)
#pragma unroll
                for (int dx = 0; dx < 3; ++dx)
                    in[dy * 3 + dx] = sIn[(ic * 18 + ty + dy) * 19 + tx + dx];
#pragma unroll
            for (int oc = 0; oc < 32; ++oc) {
                const float* wp = wbase + oc * 1152 + ic * 9;  // wave-uniform
                float s = acc[oc];
#pragma unroll
                for (int t = 0; t < 9; ++t) s += in[t] * wp[t];
                acc[oc] = s;
            }
        }
    }
    const int y = y0 + ty, x = x0 + tx;
    float* op = feat + (((size_t)b * HH + y) * WW + x) * CC + ocg * 32;
#pragma unroll
    for (int oc = 0; oc < 32; ++oc) op[oc] = acc[oc] + b1[ocg * 32 + oc];
}

// ---------------------------------------------------------------------------
// Kernel B: offset (18 ch) + mod (9 ch, 2*sigmoid) conv from NHWC feat.
// Output om[B,H,W,27]: [0..17]=offset (dy,dx interleaved per tap), [18..26]=mod.
// ---------------------------------------------------------------------------
__global__ __launch_bounds__(256)
void offmod_kernel(const float* __restrict__ feat, const float* __restrict__ Woff,
                   const float* __restrict__ boff, const float* __restrict__ Wmod,
                   const float* __restrict__ bmod, float* __restrict__ om)
{
    const int tx = threadIdx.x & 15;
    const int ty = threadIdx.x >> 4;
    const int x0 = blockIdx.x * 16;
    const int y0 = blockIdx.y * 16;
    const int b  = blockIdx.z;

    __shared__ float sIn[18 * 18 * 17];   // [iy][ix][c16 pad17] 22.0 KB

    float acc[27];
#pragma unroll
    for (int i = 0; i < 27; ++i) acc[i] = 0.f;

    for (int chunk = 0; chunk < 4; ++chunk) {
        const int c0 = chunk * 16;
        __syncthreads();
        for (int idx = threadIdx.x; idx < 324 * 4; idx += 256) {
            const int site = idx >> 2;
            const int q = idx & 3;
            const int iy = site / 18;
            const int ix = site - iy * 18;
            const int gy = y0 + iy - 1;
            const int gx = x0 + ix - 1;
            float4 v = make_float4(0.f, 0.f, 0.f, 0.f);
            if ((unsigned)gy < HH && (unsigned)gx < WW)
                v = *(const float4*)(feat + (((size_t)b * HH + gy) * WW + gx) * CC + c0 + q * 4);
            float* d = &sIn[(iy * 18 + ix) * 17 + q * 4];
            d[0] = v.x; d[1] = v.y; d[2] = v.z; d[3] = v.w;
        }
        __syncthreads();
        for (int c = 0; c < 16; ++c) {
            float in[9];
#pragma unroll
            for (int dy = 0; dy < 3; ++dy)
#pragma unroll
                for (int dx = 0; dx < 3; ++dx)
                    in[dy * 3 + dx] = sIn[((ty + dy) * 18 + tx + dx) * 17 + c];
            const int cglob = c0 + c;
#pragma unroll
            for (int o = 0; o < 18; ++o) {
                const float* wp = Woff + (size_t)o * 576 + cglob * 9;  // uniform
                float s = acc[o];
#pragma unroll
                for (int t = 0; t < 9; ++t) s += in[t] * wp[t];
                acc[o] = s;
            }
#pragma unroll
            for (int o = 0; o < 9; ++o) {
                const float* wp = Wmod + (size_t)o * 576 + cglob * 9;  // uniform
                float s = acc[18 + o];
#pragma unroll
                for (int t = 0; t < 9; ++t) s += in[t] * wp[t];
                acc[18 + o] = s;
            }
        }
    }
    const int y = y0 + ty, x = x0 + tx;
    float* op = om + (((size_t)b * HH + y) * WW + x) * 27;
#pragma unroll
    for (int o = 0; o < 18; ++o) op[o] = acc[o] + boff[o];
#pragma unroll
    for (int o = 0; o < 9; ++o) {
        const float z = acc[18 + o] + bmod[o];
        op[18 + o] = 2.f / (1.f + expf(-z));
    }
}

// ---------------------------------------------------------------------------
// Kernel D: Wdcn [oc][c][k] -> Wt [k][c][oc] for contiguous per-k staging.
// ---------------------------------------------------------------------------
__global__ void wtrans_kernel(const float* __restrict__ Wdcn, float* __restrict__ Wt)
{
    const int idx = blockIdx.x * 256 + threadIdx.x;
    if (idx >= 9 * 64 * 64) return;
    const int oc = idx & 63;
    const int t  = idx >> 6;
    const int c  = t & 63;
    const int k  = t >> 6;
    Wt[idx] = Wdcn[(size_t)(oc * 64 + c) * 9 + k];
}

// ---------------------------------------------------------------------------
// Kernel C: deformable sampling + modulated einsum.
// Block = 256 threads, 64 pixels (8x8 tile). Loop k: gather V_k[64p][64c] into
// LDS (thread = (pixel, 16-ch group), float4 corner loads from NHWC feat),
// stage Wt_k[64c][64oc], then 4x4-register-tile GEMM accumulation.
// ---------------------------------------------------------------------------
__global__ __launch_bounds__(256)
void dcn_kernel(const float* __restrict__ feat, const float* __restrict__ om,
                const float* __restrict__ Wt, const float* __restrict__ bdcn,
                float* __restrict__ out)
{
    __shared__ float sV[64 * 68];    // [p][c] stride 68 (bank spread, 16B align)
    __shared__ float sW[64 * 64];    // [c][oc]
    __shared__ float sOm[64 * 28];   // [p][27 pad28]

    const int b  = blockIdx.z;
    const int x0 = blockIdx.x * 8;
    const int y0 = blockIdx.y * 8;

    for (int idx = threadIdx.x; idx < 64 * 27; idx += 256) {
        const int p = idx / 27;
        const int j = idx - p * 27;
        const int y = y0 + (p >> 3), x = x0 + (p & 7);
        sOm[p * 28 + j] = om[(((size_t)b * HH + y) * WW + x) * 27 + j];
    }

    // phase-1 mapping: thread = (pixel p1, channel group cg of 16)
    const int p1 = threadIdx.x >> 2;
    const int cg = threadIdx.x & 3;
    const int cb = cg * 16;
    const int yy = y0 + (p1 >> 3);
    const int xx = x0 + (p1 & 7);

    // phase-2 mapping: thread = (pixel row group pr, oc group ocr)
    const int pr  = threadIdx.x >> 4;   // 0..15 -> pixels pr*4..pr*4+3
    const int ocr = threadIdx.x & 15;   // oc ocr*4..ocr*4+3

    float acc[4][4];
#pragma unroll
    for (int i = 0; i < 4; ++i)
#pragma unroll
        for (int j = 0; j < 4; ++j) acc[i][j] = 0.f;

    const float* featb = feat + (size_t)b * HH * WW * CC;

    for (int k = 0; k < 9; ++k) {
        __syncthreads();   // protects sV/sW reuse + covers sOm staging (k=0)

        // stage weights for this tap
        for (int idx = threadIdx.x; idx < 4096; idx += 256)
            sW[idx] = Wt[k * 4096 + idx];

        // ---- gather phase ----
        const float dy = sOm[p1 * 28 + 2 * k];
        const float dx = sOm[p1 * 28 + 2 * k + 1];
        const float m  = sOm[p1 * 28 + 18 + k];
        const float pyf = (float)(yy + (k / 3) - 1) + dy;
        const float pxf = (float)(xx + (k % 3) - 1) + dx;
        const float fy0 = floorf(pyf), fx0 = floorf(pxf);
        const float wy1 = pyf - fy0, wx1 = pxf - fx0;
        const int iy0 = (int)fy0, ix0 = (int)fx0;
        const float w00 = (1.f - wy1) * (1.f - wx1);
        const float w01 = (1.f - wy1) * wx1;
        const float w10 = wy1 * (1.f - wx1);
        const float w11 = wy1 * wx1;

        float4 s0 = make_float4(0.f, 0.f, 0.f, 0.f);
        float4 s1 = s0, s2 = s0, s3 = s0;

        auto corner = [&](int yc, int xc, float wgt) {
            const bool valid = ((unsigned)yc < (unsigned)HH) && ((unsigned)xc < (unsigned)WW);
            const float wv = valid ? wgt : 0.f;
            const int yi = valid ? yc : 0;
            const int xi = valid ? xc : 0;
            const float* cp = featb + ((size_t)(yi * WW + xi)) * CC + cb;
            const float4 a0 = *(const float4*)(cp + 0);
            const float4 a1 = *(const float4*)(cp + 4);
            const float4 a2 = *(const float4*)(cp + 8);
            const float4 a3 = *(const float4*)(cp + 12);
            s0.x += wv * a0.x; s0.y += wv * a0.y; s0.z += wv * a0.z; s0.w += wv * a0.w;
            s1.x += wv * a1.x; s1.y += wv * a1.y; s1.z += wv * a1.z; s1.w += wv * a1.w;
            s2.x += wv * a2.x; s2.y += wv * a2.y; s2.z += wv * a2.z; s2.w += wv * a2.w;
            s3.x += wv * a3.x; s3.y += wv * a3.y; s3.z += wv * a3.z; s3.w += wv * a3.w;
        };
        corner(iy0,     ix0,     w00);
        corner(iy0,     ix0 + 1, w01);
        corner(iy0 + 1, ix0,     w10);
        corner(iy0 + 1, ix0 + 1, w11);

        float* vp = &sV[p1 * 68 + cb];
        *(float4*)(vp + 0)  = make_float4(m * s0.x, m * s0.y, m * s0.z, m * s0.w);
        *(float4*)(vp + 4)  = make_float4(m * s1.x, m * s1.y, m * s1.z, m * s1.w);
        *(float4*)(vp + 8)  = make_float4(m * s2.x, m * s2.y, m * s2.z, m * s2.w);
        *(float4*)(vp + 12) = make_float4(m * s3.x, m * s3.y, m * s3.z, m * s3.w);

        __syncthreads();

        // ---- GEMM phase: acc[i][j] += V[pr*4+i][c] * sW[c][ocr*4+j] ----
#pragma unroll 4
        for (int c = 0; c < 64; c += 4) {
            const float4 v0 = *(const float4*)&sV[(pr * 4 + 0) * 68 + c];
            const float4 v1 = *(const float4*)&sV[(pr * 4 + 1) * 68 + c];
            const float4 v2 = *(const float4*)&sV[(pr * 4 + 2) * 68 + c];
            const float4 v3 = *(const float4*)&sV[(pr * 4 + 3) * 68 + c];
            const float4 wq0 = *(const float4*)&sW[(c + 0) * 64 + ocr * 4];
            const float4 wq1 = *(const float4*)&sW[(c + 1) * 64 + ocr * 4];
            const float4 wq2 = *(const float4*)&sW[(c + 2) * 64 + ocr * 4];
            const float4 wq3 = *(const float4*)&sW[(c + 3) * 64 + ocr * 4];
#define DCN_STEP(vi, i) \
            acc[i][0] += vi.x * wq0.x + vi.y * wq1.x + vi.z * wq2.x + vi.w * wq3.x; \
            acc[i][1] += vi.x * wq0.y + vi.y * wq1.y + vi.z * wq2.y + vi.w * wq3.y; \
            acc[i][2] += vi.x * wq0.z + vi.y * wq1.z + vi.z * wq2.z + vi.w * wq3.z; \
            acc[i][3] += vi.x * wq0.w + vi.y * wq1.w + vi.z * wq2.w + vi.w * wq3.w;
            DCN_STEP(v0, 0)
            DCN_STEP(v1, 1)
            DCN_STEP(v2, 2)
            DCN_STEP(v3, 3)
#undef DCN_STEP
        }
    }

    // epilogue: out is NCHW
#pragma unroll
    for (int i = 0; i < 4; ++i) {
        const int p = pr * 4 + i;
        const int y = y0 + (p >> 3), x = x0 + (p & 7);
#pragma unroll
        for (int j = 0; j < 4; ++j) {
            const int oc = ocr * 4 + j;
            out[(((size_t)b * CC + oc) * HH + y) * WW + x] = acc[i][j] + bdcn[oc];
        }
    }
}

extern "C" void kernel_launch(void* const* d_in, const int* in_sizes, int n_in,
                              void* d_out, int out_size, void* d_ws, size_t ws_size,
                              hipStream_t stream)
{
    const float* xvq  = (const float*)d_in[0];
    const float* xres = (const float*)d_in[1];
    const float* W1   = (const float*)d_in[2];
    const float* b1   = (const float*)d_in[3];
    const float* Woff = (const float*)d_in[4];
    const float* boff = (const float*)d_in[5];
    const float* Wmod = (const float*)d_in[6];
    const float* bmod = (const float*)d_in[7];
    const float* Wdcn = (const float*)d_in[8];
    const float* bdcn = (const float*)d_in[9];
    float* out = (float*)d_out;

    float* feat = (float*)d_ws;                         // B*H*W*64  (33.5 MB)
    float* om   = feat + (size_t)BB * HH * WW * CC;     // B*H*W*27  (14.2 MB)
    float* Wt   = om + (size_t)BB * HH * WW * 27;       // 9*64*64   (0.14 MB)

    conv1_kernel<<<dim3(8, 8, 16), 256, 0, stream>>>(xvq, xres, W1, b1, feat);
    wtrans_kernel<<<dim3(144), 256, 0, stream>>>(Wdcn, Wt);
    offmod_kernel<<<dim3(8, 8, 8), 256, 0, stream>>>(feat, Woff, boff, Wmod, bmod, om);
    dcn_kernel<<<dim3(16, 16, 8), 256, 0, stream>>>(feat, om, Wt, bdcn, out);
}

// Round 2
// 588.870 us; speedup vs baseline: 2.0804x; 2.0804x over previous
//
#include <hip/hip_runtime.h>
#include <cmath>

#define BB 8
#define CC 64
#define HH 128
#define WW 128

typedef short s8v __attribute__((ext_vector_type(8)));   // 8 bf16 (4 VGPRs)
typedef float f4v __attribute__((ext_vector_type(4)));   // 4 fp32 acc
typedef unsigned short u16;
typedef u16 u4v __attribute__((ext_vector_type(4)));

__device__ __forceinline__ u16 f2bf(float f) {
    union { float f; unsigned u; } v; v.f = f;
    unsigned r = v.u + 0x7fff + ((v.u >> 16) & 1);   // RTNE
    return (u16)(r >> 16);
}

// ---------------------------------------------------------------------------
// Kernel 0: NCHW fp32 (x_vq ++ x_res) -> NHWC bf16 xin[B][H][W][128]
// LDS transpose per (b,h) row: coalesced fp32 reads, coalesced ushort4 writes.
// ---------------------------------------------------------------------------
__global__ __launch_bounds__(256)
void x2nhwc_kernel(const float* __restrict__ xvq, const float* __restrict__ xres,
                   u16* __restrict__ xout)
{
    const int h = blockIdx.x;
    const int b = blockIdx.y;
    __shared__ u16 lds[128 * 132];   // [w][c] pad->132 (2-bank lane shift, free)

    for (int i = 0; i < 64; ++i) {
        const int idx = threadIdx.x + 256 * i;       // 16384 elems
        const int c = idx >> 7;
        const int w = idx & 127;
        const float v = (c < 64)
            ? xvq[(((size_t)b * 64 + c) * HH + h) * WW + w]
            : xres[(((size_t)b * 64 + (c - 64)) * HH + h) * WW + w];
        lds[w * 132 + c] = f2bf(v);
    }
    __syncthreads();
    u16* orow = xout + (((size_t)b * HH + h) * WW) * 128;
    for (int i = 0; i < 16; ++i) {
        const int idx = threadIdx.x + 256 * i;       // 4096 ushort4
        const int w = idx >> 5;
        const int q = idx & 31;
        *(u4v*)(orow + (size_t)w * 128 + q * 4) = *(const u4v*)&lds[w * 132 + q * 4];
    }
}

// ---------------------------------------------------------------------------
// Kernel 0b: W1 [oc64][ic128][3][3] fp32 -> W1t [tap9][oc64][ic128] bf16
// ---------------------------------------------------------------------------
__global__ void w1trans_kernel(const float* __restrict__ W1, u16* __restrict__ W1t)
{
    const int idx = blockIdx.x * 256 + threadIdx.x;
    if (idx >= 9 * 64 * 128) return;
    const int ic = idx & 127;
    const int oc = (idx >> 7) & 63;
    const int t  = idx >> 13;
    W1t[idx] = f2bf(W1[((size_t)(oc * 128 + ic)) * 9 + t]);
}

// ---------------------------------------------------------------------------
// Kernel A: conv1 as implicit-GEMM bf16 MFMA.
// Block: 8x8 pixels x 64 oc, 4 waves; wave(wi,wj) = 32 px x 32 oc,
// 2x2 tiles of mfma_f32_16x16x32_bf16, K = 9 taps x 128 ic.
// feat out: fp32 NHWC [B][H][W][64].
// ---------------------------------------------------------------------------
__global__ __launch_bounds__(256)
void conv1_mfma_kernel(const u16* __restrict__ xin, const u16* __restrict__ W1t,
                       const float* __restrict__ b1, float* __restrict__ feat)
{
    __shared__ u16 sTile[100 * 136];  // [10x10 spatial][ic128 pad136] 27.2 KB
    __shared__ u16 sW[64 * 136];      // [oc][ic128 pad136] 17.4 KB

    const int x0 = blockIdx.x * 8;
    const int y0 = blockIdx.y * 8;
    const int b  = blockIdx.z;
    const int tid = threadIdx.x;
    const int lane = tid & 63;
    const int wave = tid >> 6;
    const int wi = wave >> 1;         // pixel half (0/1)
    const int wj = wave & 1;          // oc half (0/1)
    const int lm = lane & 15;
    const int kg = lane >> 4;

    // ---- stage input tile (10x10 x 128ic bf16) ----
    const u16* xb = xin + ((size_t)b * HH * WW) * 128;
    for (int i = 0; i < 7; ++i) {
        const int idx = tid + 256 * i;              // 1600 ushort8
        if (idx < 1600) {
            const int pix = idx >> 4;
            const int q   = idx & 15;
            const int gy = y0 - 1 + pix / 10;
            const int gx = x0 - 1 + pix % 10;
            s8v v = (s8v)0;
            if ((unsigned)gy < HH && (unsigned)gx < WW)
                v = *(const s8v*)(xb + ((size_t)(gy * WW + gx)) * 128 + q * 8);
            *(s8v*)&sTile[pix * 136 + q * 8] = v;
        }
    }

    f4v acc[2][2];
#pragma unroll
    for (int i = 0; i < 2; ++i)
#pragma unroll
        for (int j = 0; j < 2; ++j) acc[i][j] = (f4v)0.f;

    for (int t = 0; t < 9; ++t) {
        __syncthreads();   // prior sW reads done (and sTile staged, t=0)
        // stage weights for tap t: [oc][ic]
        for (int i = 0; i < 4; ++i) {
            const int idx = tid + 256 * i;          // 1024 ushort8
            const int oc = idx >> 4;
            const int q  = idx & 15;
            *(s8v*)&sW[oc * 136 + q * 8] =
                *(const s8v*)(W1t + ((size_t)t * 64 + oc) * 128 + q * 8);
        }
        __syncthreads();

        const int dy = t / 3, dx = t % 3;
        // A-frags: a[mt][ks]
        s8v a[2][4];
#pragma unroll
        for (int mt = 0; mt < 2; ++mt) {
            const int p = wi * 32 + mt * 16 + lm;
            const int sidx = ((p >> 3) + dy) * 10 + (p & 7) + dx;
#pragma unroll
            for (int ks = 0; ks < 4; ++ks)
                a[mt][ks] = *(const s8v*)&sTile[sidx * 136 + ks * 32 + kg * 8];
        }
#pragma unroll
        for (int nt = 0; nt < 2; ++nt) {
            const int oc = wj * 32 + nt * 16 + lm;
            s8v bfr[4];
#pragma unroll
            for (int ks = 0; ks < 4; ++ks)
                bfr[ks] = *(const s8v*)&sW[oc * 136 + ks * 32 + kg * 8];
#pragma unroll
            for (int mt = 0; mt < 2; ++mt)
#pragma unroll
                for (int ks = 0; ks < 4; ++ks)
                    acc[mt][nt] = __builtin_amdgcn_mfma_f32_16x16x32_bf16(
                        a[mt][ks], bfr[ks], acc[mt][nt], 0, 0, 0);
        }
    }

    // ---- epilogue: C layout col=lane&15 (oc), row=(lane>>4)*4+reg (pixel) ----
#pragma unroll
    for (int mt = 0; mt < 2; ++mt)
#pragma unroll
        for (int nt = 0; nt < 2; ++nt) {
            const int oc = wj * 32 + nt * 16 + lm;
            const float bias = b1[oc];
#pragma unroll
            for (int r = 0; r < 4; ++r) {
                const int p = wi * 32 + mt * 16 + kg * 4 + r;
                const int y = y0 + (p >> 3), x = x0 + (p & 7);
                feat[(((size_t)b * HH + y) * WW + x) * CC + oc] = acc[mt][nt][r] + bias;
            }
        }
}

// ---------------------------------------------------------------------------
// Kernel B: offset (18 ch) + mod (9 ch, 2*sigmoid) conv from NHWC fp32 feat.
// Output om[B,H,W,27]: [0..17]=offset (dy,dx per tap), [18..26]=mod.
// ---------------------------------------------------------------------------
__global__ __launch_bounds__(256)
void offmod_kernel(const float* __restrict__ feat, const float* __restrict__ Woff,
                   const float* __restrict__ boff, const float* __restrict__ Wmod,
                   const float* __restrict__ bmod, float* __restrict__ om)
{
    const int tx = threadIdx.x & 15;
    const int ty = threadIdx.x >> 4;
    const int x0 = blockIdx.x * 16;
    const int y0 = blockIdx.y * 16;
    const int b  = blockIdx.z;

    __shared__ float sIn[18 * 18 * 17];   // [iy][ix][c16 pad17] 22.0 KB

    float acc[27];
#pragma unroll
    for (int i = 0; i < 27; ++i) acc[i] = 0.f;

    for (int chunk = 0; chunk < 4; ++chunk) {
        const int c0 = chunk * 16;
        __syncthreads();
        for (int idx = threadIdx.x; idx < 324 * 4; idx += 256) {
            const int site = idx >> 2;
            const int q = idx & 3;
            const int iy = site / 18;
            const int ix = site - iy * 18;
            const int gy = y0 + iy - 1;
            const int gx = x0 + ix - 1;
            float4 v = make_float4(0.f, 0.f, 0.f, 0.f);
            if ((unsigned)gy < HH && (unsigned)gx < WW)
                v = *(const float4*)(feat + (((size_t)b * HH + gy) * WW + gx) * CC + c0 + q * 4);
            float* d = &sIn[(iy * 18 + ix) * 17 + q * 4];
            d[0] = v.x; d[1] = v.y; d[2] = v.z; d[3] = v.w;
        }
        __syncthreads();
        for (int c = 0; c < 16; ++c) {
            float in[9];
#pragma unroll
            for (int dy = 0; dy < 3; ++dy)
#pragma unroll
                for (int dx = 0; dx < 3; ++dx)
                    in[dy * 3 + dx] = sIn[((ty + dy) * 18 + tx + dx) * 17 + c];
            const int cglob = c0 + c;
#pragma unroll
            for (int o = 0; o < 18; ++o) {
                const float* wp = Woff + (size_t)o * 576 + cglob * 9;  // uniform
                float s = acc[o];
#pragma unroll
                for (int t = 0; t < 9; ++t) s += in[t] * wp[t];
                acc[o] = s;
            }
#pragma unroll
            for (int o = 0; o < 9; ++o) {
                const float* wp = Wmod + (size_t)o * 576 + cglob * 9;  // uniform
                float s = acc[18 + o];
#pragma unroll
                for (int t = 0; t < 9; ++t) s += in[t] * wp[t];
                acc[18 + o] = s;
            }
        }
    }
    const int y = y0 + ty, x = x0 + tx;
    float* op = om + (((size_t)b * HH + y) * WW + x) * 27;
#pragma unroll
    for (int o = 0; o < 18; ++o) op[o] = acc[o] + boff[o];
#pragma unroll
    for (int o = 0; o < 9; ++o) {
        const float z = acc[18 + o] + bmod[o];
        op[18 + o] = 2.f / (1.f + expf(-z));
    }
}

// ---------------------------------------------------------------------------
// Kernel D: Wdcn [oc][c][k] -> Wt [k][c][oc] for contiguous per-k staging.
// ---------------------------------------------------------------------------
__global__ void wtrans_kernel(const float* __restrict__ Wdcn, float* __restrict__ Wt)
{
    const int idx = blockIdx.x * 256 + threadIdx.x;
    if (idx >= 9 * 64 * 64) return;
    const int oc = idx & 63;
    const int t  = idx >> 6;
    const int c  = t & 63;
    const int k  = t >> 6;
    Wt[idx] = Wdcn[(size_t)(oc * 64 + c) * 9 + k];
}

// ---------------------------------------------------------------------------
// Kernel C: deformable sampling + modulated einsum (fp32, unchanged).
// ---------------------------------------------------------------------------
__global__ __launch_bounds__(256)
void dcn_kernel(const float* __restrict__ feat, const float* __restrict__ om,
                const float* __restrict__ Wt, const float* __restrict__ bdcn,
                float* __restrict__ out)
{
    __shared__ float sV[64 * 68];    // [p][c] stride 68
    __shared__ float sW[64 * 64];    // [c][oc]
    __shared__ float sOm[64 * 28];   // [p][27 pad28]

    const int b  = blockIdx.z;
    const int x0 = blockIdx.x * 8;
    const int y0 = blockIdx.y * 8;

    for (int idx = threadIdx.x; idx < 64 * 27; idx += 256) {
        const int p = idx / 27;
        const int j = idx - p * 27;
        const int y = y0 + (p >> 3), x = x0 + (p & 7);
        sOm[p * 28 + j] = om[(((size_t)b * HH + y) * WW + x) * 27 + j];
    }

    const int p1 = threadIdx.x >> 2;
    const int cg = threadIdx.x & 3;
    const int cb = cg * 16;
    const int yy = y0 + (p1 >> 3);
    const int xx = x0 + (p1 & 7);

    const int pr  = threadIdx.x >> 4;
    const int ocr = threadIdx.x & 15;

    float acc[4][4];
#pragma unroll
    for (int i = 0; i < 4; ++i)
#pragma unroll
        for (int j = 0; j < 4; ++j) acc[i][j] = 0.f;

    const float* featb = feat + (size_t)b * HH * WW * CC;

    for (int k = 0; k < 9; ++k) {
        __syncthreads();

        for (int idx = threadIdx.x; idx < 4096; idx += 256)
            sW[idx] = Wt[k * 4096 + idx];

        const float dy = sOm[p1 * 28 + 2 * k];
        const float dx = sOm[p1 * 28 + 2 * k + 1];
        const float m  = sOm[p1 * 28 + 18 + k];
        const float pyf = (float)(yy + (k / 3) - 1) + dy;
        const float pxf = (float)(xx + (k % 3) - 1) + dx;
        const float fy0 = floorf(pyf), fx0 = floorf(pxf);
        const float wy1 = pyf - fy0, wx1 = pxf - fx0;
        const int iy0 = (int)fy0, ix0 = (int)fx0;
        const float w00 = (1.f - wy1) * (1.f - wx1);
        const float w01 = (1.f - wy1) * wx1;
        const float w10 = wy1 * (1.f - wx1);
        const float w11 = wy1 * wx1;

        float4 s0 = make_float4(0.f, 0.f, 0.f, 0.f);
        float4 s1 = s0, s2 = s0, s3 = s0;

        auto corner = [&](int yc, int xc, float wgt) {
            const bool valid = ((unsigned)yc < (unsigned)HH) && ((unsigned)xc < (unsigned)WW);
            const float wv = valid ? wgt : 0.f;
            const int yi = valid ? yc : 0;
            const int xi = valid ? xc : 0;
            const float* cp = featb + ((size_t)(yi * WW + xi)) * CC + cb;
            const float4 a0 = *(const float4*)(cp + 0);
            const float4 a1 = *(const float4*)(cp + 4);
            const float4 a2 = *(const float4*)(cp + 8);
            const float4 a3 = *(const float4*)(cp + 12);
            s0.x += wv * a0.x; s0.y += wv * a0.y; s0.z += wv * a0.z; s0.w += wv * a0.w;
            s1.x += wv * a1.x; s1.y += wv * a1.y; s1.z += wv * a1.z; s1.w += wv * a1.w;
            s2.x += wv * a2.x; s2.y += wv * a2.y; s2.z += wv * a2.z; s2.w += wv * a2.w;
            s3.x += wv * a3.x; s3.y += wv * a3.y; s3.z += wv * a3.z; s3.w += wv * a3.w;
        };
        corner(iy0,     ix0,     w00);
        corner(iy0,     ix0 + 1, w01);
        corner(iy0 + 1, ix0,     w10);
        corner(iy0 + 1, ix0 + 1, w11);

        float* vp = &sV[p1 * 68 + cb];
        *(float4*)(vp + 0)  = make_float4(m * s0.x, m * s0.y, m * s0.z, m * s0.w);
        *(float4*)(vp + 4)  = make_float4(m * s1.x, m * s1.y, m * s1.z, m * s1.w);
        *(float4*)(vp + 8)  = make_float4(m * s2.x, m * s2.y, m * s2.z, m * s2.w);
        *(float4*)(vp + 12) = make_float4(m * s3.x, m * s3.y, m * s3.z, m * s3.w);

        __syncthreads();

#pragma unroll 4
        for (int c = 0; c < 64; c += 4) {
            const float4 v0 = *(const float4*)&sV[(pr * 4 + 0) * 68 + c];
            const float4 v1 = *(const float4*)&sV[(pr * 4 + 1) * 68 + c];
            const float4 v2 = *(const float4*)&sV[(pr * 4 + 2) * 68 + c];
            const float4 v3 = *(const float4*)&sV[(pr * 4 + 3) * 68 + c];
            const float4 wq0 = *(const float4*)&sW[(c + 0) * 64 + ocr * 4];
            const float4 wq1 = *(const float4*)&sW[(c + 1) * 64 + ocr * 4];
            const float4 wq2 = *(const float4*)&sW[(c + 2) * 64 + ocr * 4];
            const float4 wq3 = *(const float4*)&sW[(c + 3) * 64 + ocr * 4];
#define DCN_STEP(vi, i) \
            acc[i][0] += vi.x * wq0.x + vi.y * wq1.x + vi.z * wq2.x + vi.w * wq3.x; \
            acc[i][1] += vi.x * wq0.y + vi.y * wq1.y + vi.z * wq2.y + vi.w * wq3.y; \
            acc[i][2] += vi.x * wq0.z + vi.y * wq1.z + vi.z * wq2.z + vi.w * wq3.z; \
            acc[i][3] += vi.x * wq0.w + vi.y * wq1.w + vi.z * wq2.w + vi.w * wq3.w;
            DCN_STEP(v0, 0)
            DCN_STEP(v1, 1)
            DCN_STEP(v2, 2)
            DCN_STEP(v3, 3)
#undef DCN_STEP
        }
    }

#pragma unroll
    for (int i = 0; i < 4; ++i) {
        const int p = pr * 4 + i;
        const int y = y0 + (p >> 3), x = x0 + (p & 7);
#pragma unroll
        for (int j = 0; j < 4; ++j) {
            const int oc = ocr * 4 + j;
            out[(((size_t)b * CC + oc) * HH + y) * WW + x] = acc[i][j] + bdcn[oc];
        }
    }
}

extern "C" void kernel_launch(void* const* d_in, const int* in_sizes, int n_in,
                              void* d_out, int out_size, void* d_ws, size_t ws_size,
                              hipStream_t stream)
{
    const float* xvq  = (const float*)d_in[0];
    const float* xres = (const float*)d_in[1];
    const float* W1   = (const float*)d_in[2];
    const float* b1   = (const float*)d_in[3];
    const float* Woff = (const float*)d_in[4];
    const float* boff = (const float*)d_in[5];
    const float* Wmod = (const float*)d_in[6];
    const float* bmod = (const float*)d_in[7];
    const float* Wdcn = (const float*)d_in[8];
    const float* bdcn = (const float*)d_in[9];
    float* out = (float*)d_out;

    float* feat = (float*)d_ws;                          // 8.39M f32
    float* om   = feat + (size_t)BB * HH * WW * CC;      // 3.54M f32
    float* Wt   = om + (size_t)BB * HH * WW * 27;        // 36864 f32
    u16*  xin   = (u16*)(Wt + 9 * 64 * 64);              // 16.78M bf16
    u16*  W1t   = xin + (size_t)BB * HH * WW * 128;      // 73728 bf16

    x2nhwc_kernel<<<dim3(HH, BB), 256, 0, stream>>>(xvq, xres, xin);
    w1trans_kernel<<<dim3(288), 256, 0, stream>>>(W1, W1t);
    wtrans_kernel<<<dim3(144), 256, 0, stream>>>(Wdcn, Wt);
    conv1_mfma_kernel<<<dim3(16, 16, 8), 256, 0, stream>>>(xin, W1t, b1, feat);
    offmod_kernel<<<dim3(8, 8, 8), 256, 0, stream>>>(feat, Woff, boff, Wmod, bmod, om);
    dcn_kernel<<<dim3(16, 16, 8), 256, 0, stream>>>(feat, om, Wt, bdcn, out);
}

// Round 3
// 232.166 us; speedup vs baseline: 5.2769x; 2.5364x over previous
//
#include <hip/hip_runtime.h>
#include <cmath>

#define BB 8
#define CC 64
#define HH 128
#define WW 128

typedef short s8v __attribute__((ext_vector_type(8)));   // 8 bf16 (4 VGPRs)
typedef float f4v __attribute__((ext_vector_type(4)));   // 4 fp32 acc
typedef unsigned short u16;
typedef u16 u4v __attribute__((ext_vector_type(4)));

__device__ __forceinline__ u16 f2bf(float f) {
    union { float f; unsigned u; } v; v.f = f;
    unsigned r = v.u + 0x7fff + ((v.u >> 16) & 1);   // RTNE
    return (u16)(r >> 16);
}
__device__ __forceinline__ float bf2f(short h) {
    union { unsigned u; float f; } v;
    v.u = ((unsigned)(u16)h) << 16;
    return v.f;
}

// ---------------------------------------------------------------------------
// Kernel 0: NCHW fp32 (x_vq ++ x_res) -> NHWC bf16 xin[B][H][W][128]
// ---------------------------------------------------------------------------
__global__ __launch_bounds__(256)
void x2nhwc_kernel(const float* __restrict__ xvq, const float* __restrict__ xres,
                   u16* __restrict__ xout)
{
    const int h = blockIdx.x;
    const int b = blockIdx.y;
    __shared__ u16 lds[128 * 132];

    for (int i = 0; i < 64; ++i) {
        const int idx = threadIdx.x + 256 * i;
        const int c = idx >> 7;
        const int w = idx & 127;
        const float v = (c < 64)
            ? xvq[(((size_t)b * 64 + c) * HH + h) * WW + w]
            : xres[(((size_t)b * 64 + (c - 64)) * HH + h) * WW + w];
        lds[w * 132 + c] = f2bf(v);
    }
    __syncthreads();
    u16* orow = xout + (((size_t)b * HH + h) * WW) * 128;
    for (int i = 0; i < 16; ++i) {
        const int idx = threadIdx.x + 256 * i;
        const int w = idx >> 5;
        const int q = idx & 31;
        *(u4v*)(orow + (size_t)w * 128 + q * 4) = *(const u4v*)&lds[w * 132 + q * 4];
    }
}

// W1 [oc64][ic128][3][3] fp32 -> W1t [tap9][oc64][ic128] bf16
__global__ void w1trans_kernel(const float* __restrict__ W1, u16* __restrict__ W1t)
{
    const int idx = blockIdx.x * 256 + threadIdx.x;
    if (idx >= 9 * 64 * 128) return;
    const int ic = idx & 127;
    const int oc = (idx >> 7) & 63;
    const int t  = idx >> 13;
    W1t[idx] = f2bf(W1[((size_t)(oc * 128 + ic)) * 9 + t]);
}

// Woff[18][64][3][3] + Wmod[9][64][3][3] -> Womt bf16 [tap9][o32(27 used)][c64]
__global__ void womtrans_kernel(const float* __restrict__ Woff,
                                const float* __restrict__ Wmod, u16* __restrict__ Womt)
{
    const int idx = blockIdx.x * 256 + threadIdx.x;
    if (idx >= 9 * 32 * 64) return;
    const int c = idx & 63;
    const int o = (idx >> 6) & 31;
    const int t = idx >> 11;
    float v = 0.f;
    if (o < 18)      v = Woff[((size_t)(o * 64 + c)) * 9 + t];
    else if (o < 27) v = Wmod[((size_t)((o - 18) * 64 + c)) * 9 + t];
    Womt[idx] = f2bf(v);
}

// Wdcn [oc][c][k] fp32 -> Wdt bf16 [k][oc][c]
__global__ void wdtrans_kernel(const float* __restrict__ Wdcn, u16* __restrict__ Wdt)
{
    const int idx = blockIdx.x * 256 + threadIdx.x;
    if (idx >= 9 * 64 * 64) return;
    const int c  = idx & 63;
    const int oc = (idx >> 6) & 63;
    const int k  = idx >> 12;
    Wdt[idx] = f2bf(Wdcn[((size_t)(oc * 64 + c)) * 9 + k]);
}

// ---------------------------------------------------------------------------
// Kernel A: conv1 implicit-GEMM bf16 MFMA. 8x8 px x 64 oc per block.
// feat out: bf16 NHWC [B][H][W][64].
// ---------------------------------------------------------------------------
__global__ __launch_bounds__(256)
void conv1_mfma_kernel(const u16* __restrict__ xin, const u16* __restrict__ W1t,
                       const float* __restrict__ b1, u16* __restrict__ featb)
{
    __shared__ u16 sTile[100 * 136];  // [10x10][ic128 pad136]
    __shared__ u16 sW[64 * 136];      // [oc][ic128 pad136]

    const int x0 = blockIdx.x * 8;
    const int y0 = blockIdx.y * 8;
    const int b  = blockIdx.z;
    const int tid = threadIdx.x;
    const int lane = tid & 63;
    const int wave = tid >> 6;
    const int wi = wave >> 1;
    const int wj = wave & 1;
    const int lm = lane & 15;
    const int kg = lane >> 4;

    const u16* xb = xin + ((size_t)b * HH * WW) * 128;
    for (int i = 0; i < 7; ++i) {
        const int idx = tid + 256 * i;              // 1600 ushort8
        if (idx < 1600) {
            const int pix = idx >> 4;
            const int q   = idx & 15;
            const int gy = y0 - 1 + pix / 10;
            const int gx = x0 - 1 + pix % 10;
            s8v v = (s8v)0;
            if ((unsigned)gy < HH && (unsigned)gx < WW)
                v = *(const s8v*)(xb + ((size_t)(gy * WW + gx)) * 128 + q * 8);
            *(s8v*)&sTile[pix * 136 + q * 8] = v;
        }
    }

    f4v acc[2][2];
#pragma unroll
    for (int i = 0; i < 2; ++i)
#pragma unroll
        for (int j = 0; j < 2; ++j) acc[i][j] = (f4v)0.f;

    for (int t = 0; t < 9; ++t) {
        __syncthreads();
        for (int i = 0; i < 4; ++i) {
            const int idx = tid + 256 * i;
            const int oc = idx >> 4;
            const int q  = idx & 15;
            *(s8v*)&sW[oc * 136 + q * 8] =
                *(const s8v*)(W1t + ((size_t)t * 64 + oc) * 128 + q * 8);
        }
        __syncthreads();

        const int dy = t / 3, dx = t % 3;
        s8v a[2][4];
#pragma unroll
        for (int mt = 0; mt < 2; ++mt) {
            const int p = wi * 32 + mt * 16 + lm;
            const int sidx = ((p >> 3) + dy) * 10 + (p & 7) + dx;
#pragma unroll
            for (int ks = 0; ks < 4; ++ks)
                a[mt][ks] = *(const s8v*)&sTile[sidx * 136 + ks * 32 + kg * 8];
        }
#pragma unroll
        for (int nt = 0; nt < 2; ++nt) {
            const int oc = wj * 32 + nt * 16 + lm;
            s8v bfr[4];
#pragma unroll
            for (int ks = 0; ks < 4; ++ks)
                bfr[ks] = *(const s8v*)&sW[oc * 136 + ks * 32 + kg * 8];
#pragma unroll
            for (int mt = 0; mt < 2; ++mt)
#pragma unroll
                for (int ks = 0; ks < 4; ++ks)
                    acc[mt][nt] = __builtin_amdgcn_mfma_f32_16x16x32_bf16(
                        a[mt][ks], bfr[ks], acc[mt][nt], 0, 0, 0);
        }
    }

#pragma unroll
    for (int mt = 0; mt < 2; ++mt)
#pragma unroll
        for (int nt = 0; nt < 2; ++nt) {
            const int oc = wj * 32 + nt * 16 + lm;
            const float bias = b1[oc];
#pragma unroll
            for (int r = 0; r < 4; ++r) {
                const int p = wi * 32 + mt * 16 + kg * 4 + r;
                const int y = y0 + (p >> 3), x = x0 + (p & 7);
                featb[(((size_t)b * HH + y) * WW + x) * CC + oc] =
                    f2bf(acc[mt][nt][r] + bias);
            }
        }
}

// ---------------------------------------------------------------------------
// Kernel B: offset+mod conv as bf16 MFMA. M=64px/block, N=32(27), K=9x64.
// Single barrier: all 9 taps' weights preloaded. om fp32 [B,H,W,27].
// ---------------------------------------------------------------------------
__global__ __launch_bounds__(256)
void offmod_mfma_kernel(const u16* __restrict__ featb, const u16* __restrict__ Womt,
                        const float* __restrict__ boff, const float* __restrict__ bmod,
                        float* __restrict__ om)
{
    __shared__ u16 sTile[100 * 72];    // [10x10][c64 pad72] 14.4 KB
    __shared__ u16 sWom[288 * 72];     // [t*32+o][c64 pad72] 41.5 KB

    const int x0 = blockIdx.x * 8;
    const int y0 = blockIdx.y * 8;
    const int b  = blockIdx.z;
    const int tid = threadIdx.x;
    const int lane = tid & 63;
    const int wave = tid >> 6;
    const int lm = lane & 15;
    const int kg = lane >> 4;

    const u16* fb = featb + ((size_t)b * HH * WW) * CC;
    for (int i = 0; i < 4; ++i) {
        const int idx = tid + 256 * i;              // 800 ushort8
        if (idx < 800) {
            const int pix = idx >> 3;
            const int q   = idx & 7;
            const int gy = y0 - 1 + pix / 10;
            const int gx = x0 - 1 + pix % 10;
            s8v v = (s8v)0;
            if ((unsigned)gy < HH && (unsigned)gx < WW)
                v = *(const s8v*)(fb + ((size_t)(gy * WW + gx)) * CC + q * 8);
            *(s8v*)&sTile[pix * 72 + q * 8] = v;
        }
    }
    for (int i = 0; i < 9; ++i) {
        const int idx = tid + 256 * i;              // 2304 ushort8
        const int row = idx >> 3;
        const int q   = idx & 7;
        *(s8v*)&sWom[row * 72 + q * 8] = *(const s8v*)(Womt + (size_t)row * 64 + q * 8);
    }
    __syncthreads();

    f4v acc[2];
    acc[0] = (f4v)0.f; acc[1] = (f4v)0.f;

    const int p = wave * 16 + lm;     // A-row pixel
    const int prow = p >> 3, pcol = p & 7;

    for (int t = 0; t < 9; ++t) {
        const int dy = t / 3, dx = t % 3;
        const int sidx = (prow + dy) * 10 + pcol + dx;
        s8v a[2];
#pragma unroll
        for (int ks = 0; ks < 2; ++ks)
            a[ks] = *(const s8v*)&sTile[sidx * 72 + ks * 32 + kg * 8];
#pragma unroll
        for (int nt = 0; nt < 2; ++nt) {
            const int o = nt * 16 + lm;
#pragma unroll
            for (int ks = 0; ks < 2; ++ks) {
                const s8v bf = *(const s8v*)&sWom[(t * 32 + o) * 72 + ks * 32 + kg * 8];
                acc[nt] = __builtin_amdgcn_mfma_f32_16x16x32_bf16(a[ks], bf, acc[nt], 0, 0, 0);
            }
        }
    }

#pragma unroll
    for (int nt = 0; nt < 2; ++nt) {
        const int o = nt * 16 + lm;
        if (o >= 27) continue;
#pragma unroll
        for (int r = 0; r < 4; ++r) {
            const int pp = wave * 16 + kg * 4 + r;
            const int y = y0 + (pp >> 3), x = x0 + (pp & 7);
            float* op = om + (((size_t)b * HH + y) * WW + x) * 27;
            if (o < 18) op[o] = acc[nt][r] + boff[o];
            else {
                const float z = acc[nt][r] + bmod[o - 18];
                op[o] = 2.f / (1.f + expf(-z));
            }
        }
    }
}

// ---------------------------------------------------------------------------
// Kernel C: deformable sampling (bf16 feat gather, fp32 bilinear) +
// modulated einsum as per-tap 64x64x64 bf16 MFMA.
// ---------------------------------------------------------------------------
__global__ __launch_bounds__(256)
void dcn_mfma_kernel(const u16* __restrict__ featb, const float* __restrict__ om,
                     const u16* __restrict__ Wdt, const float* __restrict__ bdcn,
                     float* __restrict__ out)
{
    __shared__ u16 sV[64 * 72];      // [p][c64 pad72] 9.2 KB
    __shared__ u16 sWd[64 * 72];     // [oc][c64 pad72] 9.2 KB
    __shared__ float sOm[64 * 28];   // [p][27 pad28] 7.2 KB

    const int b  = blockIdx.z;
    const int x0 = blockIdx.x * 8;
    const int y0 = blockIdx.y * 8;
    const int tid = threadIdx.x;
    const int lane = tid & 63;
    const int wave = tid >> 6;
    const int wi = wave >> 1;
    const int wj = wave & 1;
    const int lm = lane & 15;
    const int kg = lane >> 4;

    for (int idx = tid; idx < 64 * 27; idx += 256) {
        const int p = idx / 27;
        const int j = idx - p * 27;
        const int y = y0 + (p >> 3), x = x0 + (p & 7);
        sOm[p * 28 + j] = om[(((size_t)b * HH + y) * WW + x) * 27 + j];
    }

    // gather mapping: thread = (pixel p1, 16-ch group cg)
    const int p1 = tid >> 2;
    const int cb = (tid & 3) * 16;
    const int yy = y0 + (p1 >> 3);
    const int xx = x0 + (p1 & 7);

    f4v acc[2][2];
#pragma unroll
    for (int i = 0; i < 2; ++i)
#pragma unroll
        for (int j = 0; j < 2; ++j) acc[i][j] = (f4v)0.f;

    const u16* fb = featb + ((size_t)b * HH * WW) * CC;

    for (int k = 0; k < 9; ++k) {
        __syncthreads();   // prev-tap LDS reads done (k=0: covers sOm staging)

        // stage weights [oc][c] for tap k
        for (int i = 0; i < 2; ++i) {
            const int idx = tid + 256 * i;          // 512 ushort8
            const int oc = idx >> 3;
            const int q  = idx & 7;
            *(s8v*)&sWd[oc * 72 + q * 8] =
                *(const s8v*)(Wdt + ((size_t)k * 64 + oc) * 64 + q * 8);
        }

        // ---- gather ----
        const float dy = sOm[p1 * 28 + 2 * k];
        const float dx = sOm[p1 * 28 + 2 * k + 1];
        const float m  = sOm[p1 * 28 + 18 + k];
        const float pyf = (float)(yy + (k / 3) - 1) + dy;
        const float pxf = (float)(xx + (k % 3) - 1) + dx;
        const float fy0 = floorf(pyf), fx0 = floorf(pxf);
        const float wy1 = pyf - fy0, wx1 = pxf - fx0;
        const int iy0 = (int)fy0, ix0 = (int)fx0;
        const float w00 = (1.f - wy1) * (1.f - wx1);
        const float w01 = (1.f - wy1) * wx1;
        const float w10 = wy1 * (1.f - wx1);
        const float w11 = wy1 * wx1;

        float s[16];
#pragma unroll
        for (int i = 0; i < 16; ++i) s[i] = 0.f;

        auto corner = [&](int yc, int xc, float wgt) {
            const bool valid = ((unsigned)yc < (unsigned)HH) && ((unsigned)xc < (unsigned)WW);
            const float wv = valid ? wgt : 0.f;
            const int yi = valid ? yc : 0;
            const int xi = valid ? xc : 0;
            const u16* cp = fb + ((size_t)(yi * WW + xi)) * CC + cb;
            const s8v a0 = *(const s8v*)(cp + 0);
            const s8v a1 = *(const s8v*)(cp + 8);
#pragma unroll
            for (int i = 0; i < 8; ++i) s[i]     += wv * bf2f(a0[i]);
#pragma unroll
            for (int i = 0; i < 8; ++i) s[8 + i] += wv * bf2f(a1[i]);
        };
        corner(iy0,     ix0,     w00);
        corner(iy0,     ix0 + 1, w01);
        corner(iy0 + 1, ix0,     w10);
        corner(iy0 + 1, ix0 + 1, w11);

        s8v v0, v1;
#pragma unroll
        for (int i = 0; i < 8; ++i) v0[i] = (short)f2bf(m * s[i]);
#pragma unroll
        for (int i = 0; i < 8; ++i) v1[i] = (short)f2bf(m * s[8 + i]);
        *(s8v*)&sV[p1 * 72 + cb]     = v0;
        *(s8v*)&sV[p1 * 72 + cb + 8] = v1;

        __syncthreads();

        // ---- GEMM: acc += V[64p][64c] * Wd[64c][64oc] ----
        s8v a[2][2], bf[2][2];
#pragma unroll
        for (int mt = 0; mt < 2; ++mt) {
            const int p = wi * 32 + mt * 16 + lm;
#pragma unroll
            for (int ks = 0; ks < 2; ++ks)
                a[mt][ks] = *(const s8v*)&sV[p * 72 + ks * 32 + kg * 8];
        }
#pragma unroll
        for (int nt = 0; nt < 2; ++nt) {
            const int oc = wj * 32 + nt * 16 + lm;
#pragma unroll
            for (int ks = 0; ks < 2; ++ks)
                bf[nt][ks] = *(const s8v*)&sWd[oc * 72 + ks * 32 + kg * 8];
        }
#pragma unroll
        for (int mt = 0; mt < 2; ++mt)
#pragma unroll
            for (int nt = 0; nt < 2; ++nt)
#pragma unroll
                for (int ks = 0; ks < 2; ++ks)
                    acc[mt][nt] = __builtin_amdgcn_mfma_f32_16x16x32_bf16(
                        a[mt][ks], bf[nt][ks], acc[mt][nt], 0, 0, 0);
    }

    // epilogue: NCHW fp32
#pragma unroll
    for (int mt = 0; mt < 2; ++mt)
#pragma unroll
        for (int nt = 0; nt < 2; ++nt) {
            const int oc = wj * 32 + nt * 16 + lm;
            const float bias = bdcn[oc];
#pragma unroll
            for (int r = 0; r < 4; ++r) {
                const int p = wi * 32 + mt * 16 + kg * 4 + r;
                const int y = y0 + (p >> 3), x = x0 + (p & 7);
                out[(((size_t)b * CC + oc) * HH + y) * WW + x] = acc[mt][nt][r] + bias;
            }
        }
}

extern "C" void kernel_launch(void* const* d_in, const int* in_sizes, int n_in,
                              void* d_out, int out_size, void* d_ws, size_t ws_size,
                              hipStream_t stream)
{
    const float* xvq  = (const float*)d_in[0];
    const float* xres = (const float*)d_in[1];
    const float* W1   = (const float*)d_in[2];
    const float* b1   = (const float*)d_in[3];
    const float* Woff = (const float*)d_in[4];
    const float* boff = (const float*)d_in[5];
    const float* Wmod = (const float*)d_in[6];
    const float* bmod = (const float*)d_in[7];
    const float* Wdcn = (const float*)d_in[8];
    const float* bdcn = (const float*)d_in[9];
    float* out = (float*)d_out;

    u16*  featb = (u16*)d_ws;                              // 8.39M u16
    float* om   = (float*)(featb + (size_t)BB * HH * WW * CC);  // 3.54M f32
    u16*  xin   = (u16*)(om + (size_t)BB * HH * WW * 27);  // 16.78M u16
    u16*  W1t   = xin + (size_t)BB * HH * WW * 128;        // 73728 u16
    u16*  Womt  = W1t + 9 * 64 * 128;                      // 18432 u16
    u16*  Wdt   = Womt + 9 * 32 * 64;                      // 36864 u16

    x2nhwc_kernel<<<dim3(HH, BB), 256, 0, stream>>>(xvq, xres, xin);
    w1trans_kernel<<<dim3(288), 256, 0, stream>>>(W1, W1t);
    womtrans_kernel<<<dim3(72), 256, 0, stream>>>(Woff, Wmod, Womt);
    wdtrans_kernel<<<dim3(144), 256, 0, stream>>>(Wdcn, Wdt);
    conv1_mfma_kernel<<<dim3(16, 16, 8), 256, 0, stream>>>(xin, W1t, b1, featb);
    offmod_mfma_kernel<<<dim3(16, 16, 8), 256, 0, stream>>>(featb, Womt, boff, bmod, om);
    dcn_mfma_kernel<<<dim3(16, 16, 8), 256, 0, stream>>>(featb, om, Wdt, bdcn, out);
}

// Round 4
// 223.401 us; speedup vs baseline: 5.4839x; 1.0392x over previous
//
#include <hip/hip_runtime.h>
#include <cmath>

#define BB 8
#define CC 64
#define HH 128
#define WW 128

typedef short s8v __attribute__((ext_vector_type(8)));   // 8 bf16 (4 VGPRs)
typedef float f4v __attribute__((ext_vector_type(4)));   // 4 fp32 acc
typedef unsigned short u16;
typedef u16 u4v __attribute__((ext_vector_type(4)));

__device__ __forceinline__ u16 f2bf(float f) {
    union { float f; unsigned u; } v; v.f = f;
    unsigned r = v.u + 0x7fff + ((v.u >> 16) & 1);   // RTNE
    return (u16)(r >> 16);
}
__device__ __forceinline__ float bf2f(short h) {
    union { unsigned u; float f; } v;
    v.u = ((unsigned)(u16)h) << 16;
    return v.f;
}

// ---------------------------------------------------------------------------
// Kernel 0: NCHW fp32 (x_vq ++ x_res) -> NHWC bf16 xin[B][H][W][128]
// ---------------------------------------------------------------------------
__global__ __launch_bounds__(256)
void x2nhwc_kernel(const float* __restrict__ xvq, const float* __restrict__ xres,
                   u16* __restrict__ xout)
{
    const int h = blockIdx.x;
    const int b = blockIdx.y;
    __shared__ u16 lds[128 * 132];

    for (int i = 0; i < 64; ++i) {
        const int idx = threadIdx.x + 256 * i;
        const int c = idx >> 7;
        const int w = idx & 127;
        const float v = (c < 64)
            ? xvq[(((size_t)b * 64 + c) * HH + h) * WW + w]
            : xres[(((size_t)b * 64 + (c - 64)) * HH + h) * WW + w];
        lds[w * 132 + c] = f2bf(v);
    }
    __syncthreads();
    u16* orow = xout + (((size_t)b * HH + h) * WW) * 128;
    for (int i = 0; i < 16; ++i) {
        const int idx = threadIdx.x + 256 * i;
        const int w = idx >> 5;
        const int q = idx & 31;
        *(u4v*)(orow + (size_t)w * 128 + q * 4) = *(const u4v*)&lds[w * 132 + q * 4];
    }
}

// W1 [oc64][ic128][3][3] fp32 -> W1t [tap9][oc64][ic128] bf16
__global__ void w1trans_kernel(const float* __restrict__ W1, u16* __restrict__ W1t)
{
    const int idx = blockIdx.x * 256 + threadIdx.x;
    if (idx >= 9 * 64 * 128) return;
    const int ic = idx & 127;
    const int oc = (idx >> 7) & 63;
    const int t  = idx >> 13;
    W1t[idx] = f2bf(W1[((size_t)(oc * 128 + ic)) * 9 + t]);
}

// Woff[18][64][3][3] + Wmod[9][64][3][3] -> Womt bf16 [tap9][o32(27 used)][c64]
__global__ void womtrans_kernel(const float* __restrict__ Woff,
                                const float* __restrict__ Wmod, u16* __restrict__ Womt)
{
    const int idx = blockIdx.x * 256 + threadIdx.x;
    if (idx >= 9 * 32 * 64) return;
    const int c = idx & 63;
    const int o = (idx >> 6) & 31;
    const int t = idx >> 11;
    float v = 0.f;
    if (o < 18)      v = Woff[((size_t)(o * 64 + c)) * 9 + t];
    else if (o < 27) v = Wmod[((size_t)((o - 18) * 64 + c)) * 9 + t];
    Womt[idx] = f2bf(v);
}

// Wdcn [oc][c][k] fp32 -> Wdt bf16 [k][oc][c]
__global__ void wdtrans_kernel(const float* __restrict__ Wdcn, u16* __restrict__ Wdt)
{
    const int idx = blockIdx.x * 256 + threadIdx.x;
    if (idx >= 9 * 64 * 64) return;
    const int c  = idx & 63;
    const int oc = (idx >> 6) & 63;
    const int k  = idx >> 12;
    Wdt[idx] = f2bf(Wdcn[((size_t)(oc * 64 + c)) * 9 + k]);
}

// ---------------------------------------------------------------------------
// Kernel A v2: conv1 implicit-GEMM bf16 MFMA. 16x16 px x 64 oc per block.
// K chunked by 32 ic; all 9 taps' weights for the chunk resident in LDS
// (8 barriers/block instead of 18). Wave = 64 px x 64 oc (4x4 acc tiles).
// feat out: bf16 NHWC [B][H][W][64].
// ---------------------------------------------------------------------------
__global__ __launch_bounds__(256)
void conv1_mfma_kernel(const u16* __restrict__ xin, const u16* __restrict__ W1t,
                       const float* __restrict__ b1, u16* __restrict__ featb)
{
    __shared__ u16 sTile[324 * 36];   // [18x18][ic32 pad36] 23.3 KB
    __shared__ u16 sW[576 * 36];      // [tap*64+oc][ic32 pad36] 41.5 KB

    const int x0 = blockIdx.x * 16;
    const int y0 = blockIdx.y * 16;
    const int b  = blockIdx.z;
    const int tid = threadIdx.x;
    const int lane = tid & 63;
    const int wave = tid >> 6;
    const int lm = lane & 15;
    const int kg = lane >> 4;

    const u16* xb = xin + ((size_t)b * HH * WW) * 128;

    f4v acc[4][4];
#pragma unroll
    for (int i = 0; i < 4; ++i)
#pragma unroll
        for (int j = 0; j < 4; ++j) acc[i][j] = (f4v)0.f;

    for (int chunk = 0; chunk < 4; ++chunk) {
        const int c0 = chunk * 32;
        __syncthreads();   // prior chunk's LDS reads done
        // stage A-tile: 324 px x 32ch = 1296 x 16B
        for (int i = 0; i < 6; ++i) {
            const int idx = tid + 256 * i;
            if (idx < 1296) {
                const int pix = idx >> 2;
                const int q   = idx & 3;
                const int gy = y0 - 1 + pix / 18;
                const int gx = x0 - 1 + pix % 18;
                s8v v = (s8v)0;
                if ((unsigned)gy < HH && (unsigned)gx < WW)
                    v = *(const s8v*)(xb + ((size_t)(gy * WW + gx)) * 128 + c0 + q * 8);
                *(s8v*)&sTile[pix * 36 + q * 8] = v;
            }
        }
        // stage weights: 576 rows x 32ch = 2304 x 16B
        for (int i = 0; i < 9; ++i) {
            const int idx = tid + 256 * i;
            const int row = idx >> 2;      // t*64 + oc
            const int q   = idx & 3;
            *(s8v*)&sW[row * 36 + q * 8] =
                *(const s8v*)(W1t + (size_t)row * 128 + c0 + q * 8);
        }
        __syncthreads();

#pragma unroll
        for (int t = 0; t < 9; ++t) {
            const int dy = t / 3, dx = t % 3;
            s8v a[4], bq[4];
#pragma unroll
            for (int mt = 0; mt < 4; ++mt) {
                const int p = wave * 64 + mt * 16 + lm;
                const int sidx = ((p >> 4) + dy) * 18 + (p & 15) + dx;
                a[mt] = *(const s8v*)&sTile[sidx * 36 + kg * 8];
            }
#pragma unroll
            for (int nt = 0; nt < 4; ++nt) {
                const int oc = nt * 16 + lm;
                bq[nt] = *(const s8v*)&sW[(t * 64 + oc) * 36 + kg * 8];
            }
#pragma unroll
            for (int mt = 0; mt < 4; ++mt)
#pragma unroll
                for (int nt = 0; nt < 4; ++nt)
                    acc[mt][nt] = __builtin_amdgcn_mfma_f32_16x16x32_bf16(
                        a[mt], bq[nt], acc[mt][nt], 0, 0, 0);
        }
    }

    // epilogue: C layout col=lane&15 (oc), row=kg*4+r (pixel)
#pragma unroll
    for (int nt = 0; nt < 4; ++nt) {
        const int oc = nt * 16 + lm;
        const float bias = b1[oc];
#pragma unroll
        for (int mt = 0; mt < 4; ++mt)
#pragma unroll
            for (int r = 0; r < 4; ++r) {
                const int p = wave * 64 + mt * 16 + kg * 4 + r;
                const int y = y0 + (p >> 4), x = x0 + (p & 15);
                featb[(((size_t)b * HH + y) * WW + x) * CC + oc] =
                    f2bf(acc[mt][nt][r] + bias);
            }
    }
}

// ---------------------------------------------------------------------------
// Kernel B v2: offset+mod conv, 16x16 px x 32(27) out per block, bf16 MFMA.
// 2 ic-chunks of 32; all 9 taps' weights resident. om fp32 [B,H,W,27].
// ---------------------------------------------------------------------------
__global__ __launch_bounds__(256)
void offmod_mfma_kernel(const u16* __restrict__ featb, const u16* __restrict__ Womt,
                        const float* __restrict__ boff, const float* __restrict__ bmod,
                        float* __restrict__ om)
{
    __shared__ u16 sTile[324 * 36];   // [18x18][c32 pad36] 23.3 KB
    __shared__ u16 sWom[288 * 36];    // [t*32+o][c32 pad36] 20.7 KB

    const int x0 = blockIdx.x * 16;
    const int y0 = blockIdx.y * 16;
    const int b  = blockIdx.z;
    const int tid = threadIdx.x;
    const int lane = tid & 63;
    const int wave = tid >> 6;
    const int lm = lane & 15;
    const int kg = lane >> 4;

    const u16* fb = featb + ((size_t)b * HH * WW) * CC;

    f4v acc[4][2];
#pragma unroll
    for (int i = 0; i < 4; ++i)
#pragma unroll
        for (int j = 0; j < 2; ++j) acc[i][j] = (f4v)0.f;

    for (int chunk = 0; chunk < 2; ++chunk) {
        const int c0 = chunk * 32;
        __syncthreads();
        for (int i = 0; i < 6; ++i) {
            const int idx = tid + 256 * i;
            if (idx < 1296) {
                const int pix = idx >> 2;
                const int q   = idx & 3;
                const int gy = y0 - 1 + pix / 18;
                const int gx = x0 - 1 + pix % 18;
                s8v v = (s8v)0;
                if ((unsigned)gy < HH && (unsigned)gx < WW)
                    v = *(const s8v*)(fb + ((size_t)(gy * WW + gx)) * CC + c0 + q * 8);
                *(s8v*)&sTile[pix * 36 + q * 8] = v;
            }
        }
        for (int i = 0; i < 5; ++i) {
            const int idx = tid + 256 * i;
            if (idx < 1152) {
                const int row = idx >> 2;     // t*32 + o
                const int q   = idx & 3;
                *(s8v*)&sWom[row * 36 + q * 8] =
                    *(const s8v*)(Womt + (size_t)row * 64 + c0 + q * 8);
            }
        }
        __syncthreads();

#pragma unroll
        for (int t = 0; t < 9; ++t) {
            const int dy = t / 3, dx = t % 3;
            s8v a[4], bq[2];
#pragma unroll
            for (int mt = 0; mt < 4; ++mt) {
                const int p = wave * 64 + mt * 16 + lm;
                const int sidx = ((p >> 4) + dy) * 18 + (p & 15) + dx;
                a[mt] = *(const s8v*)&sTile[sidx * 36 + kg * 8];
            }
#pragma unroll
            for (int nt = 0; nt < 2; ++nt) {
                const int o = nt * 16 + lm;
                bq[nt] = *(const s8v*)&sWom[(t * 32 + o) * 36 + kg * 8];
            }
#pragma unroll
            for (int mt = 0; mt < 4; ++mt)
#pragma unroll
                for (int nt = 0; nt < 2; ++nt)
                    acc[mt][nt] = __builtin_amdgcn_mfma_f32_16x16x32_bf16(
                        a[mt], bq[nt], acc[mt][nt], 0, 0, 0);
        }
    }

#pragma unroll
    for (int nt = 0; nt < 2; ++nt) {
        const int o = nt * 16 + lm;
        if (o >= 27) continue;
#pragma unroll
        for (int mt = 0; mt < 4; ++mt)
#pragma unroll
            for (int r = 0; r < 4; ++r) {
                const int p = wave * 64 + mt * 16 + kg * 4 + r;
                const int y = y0 + (p >> 4), x = x0 + (p & 15);
                float* op = om + (((size_t)b * HH + y) * WW + x) * 27;
                if (o < 18) op[o] = acc[mt][nt][r] + boff[o];
                else {
                    const float z = acc[mt][nt][r] + bmod[o - 18];
                    op[o] = 2.f / (1.f + expf(-z));
                }
            }
    }
}

// ---------------------------------------------------------------------------
// Kernel C: deformable sampling (bf16 feat gather, fp32 bilinear) +
// modulated einsum as per-tap 64x64x64 bf16 MFMA. (unchanged from r3)
// ---------------------------------------------------------------------------
__global__ __launch_bounds__(256)
void dcn_mfma_kernel(const u16* __restrict__ featb, const float* __restrict__ om,
                     const u16* __restrict__ Wdt, const float* __restrict__ bdcn,
                     float* __restrict__ out)
{
    __shared__ u16 sV[64 * 72];      // [p][c64 pad72] 9.2 KB
    __shared__ u16 sWd[64 * 72];     // [oc][c64 pad72] 9.2 KB
    __shared__ float sOm[64 * 28];   // [p][27 pad28] 7.2 KB

    const int b  = blockIdx.z;
    const int x0 = blockIdx.x * 8;
    const int y0 = blockIdx.y * 8;
    const int tid = threadIdx.x;
    const int lane = tid & 63;
    const int wave = tid >> 6;
    const int wi = wave >> 1;
    const int wj = wave & 1;
    const int lm = lane & 15;
    const int kg = lane >> 4;

    for (int idx = tid; idx < 64 * 27; idx += 256) {
        const int p = idx / 27;
        const int j = idx - p * 27;
        const int y = y0 + (p >> 3), x = x0 + (p & 7);
        sOm[p * 28 + j] = om[(((size_t)b * HH + y) * WW + x) * 27 + j];
    }

    const int p1 = tid >> 2;
    const int cb = (tid & 3) * 16;
    const int yy = y0 + (p1 >> 3);
    const int xx = x0 + (p1 & 7);

    f4v acc[2][2];
#pragma unroll
    for (int i = 0; i < 2; ++i)
#pragma unroll
        for (int j = 0; j < 2; ++j) acc[i][j] = (f4v)0.f;

    const u16* fb = featb + ((size_t)b * HH * WW) * CC;

    for (int k = 0; k < 9; ++k) {
        __syncthreads();

        for (int i = 0; i < 2; ++i) {
            const int idx = tid + 256 * i;
            const int oc = idx >> 3;
            const int q  = idx & 7;
            *(s8v*)&sWd[oc * 72 + q * 8] =
                *(const s8v*)(Wdt + ((size_t)k * 64 + oc) * 64 + q * 8);
        }

        const float dy = sOm[p1 * 28 + 2 * k];
        const float dx = sOm[p1 * 28 + 2 * k + 1];
        const float m  = sOm[p1 * 28 + 18 + k];
        const float pyf = (float)(yy + (k / 3) - 1) + dy;
        const float pxf = (float)(xx + (k % 3) - 1) + dx;
        const float fy0 = floorf(pyf), fx0 = floorf(pxf);
        const float wy1 = pyf - fy0, wx1 = pxf - fx0;
        const int iy0 = (int)fy0, ix0 = (int)fx0;
        const float w00 = m * (1.f - wy1) * (1.f - wx1);
        const float w01 = m * (1.f - wy1) * wx1;
        const float w10 = m * wy1 * (1.f - wx1);
        const float w11 = m * wy1 * wx1;

        float s[16];
#pragma unroll
        for (int i = 0; i < 16; ++i) s[i] = 0.f;

        auto corner = [&](int yc, int xc, float wgt) {
            const bool valid = ((unsigned)yc < (unsigned)HH) && ((unsigned)xc < (unsigned)WW);
            const float wv = valid ? wgt : 0.f;
            const int yi = valid ? yc : 0;
            const int xi = valid ? xc : 0;
            const u16* cp = fb + ((size_t)(yi * WW + xi)) * CC + cb;
            const s8v a0 = *(const s8v*)(cp + 0);
            const s8v a1 = *(const s8v*)(cp + 8);
#pragma unroll
            for (int i = 0; i < 8; ++i) s[i]     += wv * bf2f(a0[i]);
#pragma unroll
            for (int i = 0; i < 8; ++i) s[8 + i] += wv * bf2f(a1[i]);
        };
        corner(iy0,     ix0,     w00);
        corner(iy0,     ix0 + 1, w01);
        corner(iy0 + 1, ix0,     w10);
        corner(iy0 + 1, ix0 + 1, w11);

        s8v v0, v1;
#pragma unroll
        for (int i = 0; i < 8; ++i) v0[i] = (short)f2bf(s[i]);
#pragma unroll
        for (int i = 0; i < 8; ++i) v1[i] = (short)f2bf(s[8 + i]);
        *(s8v*)&sV[p1 * 72 + cb]     = v0;
        *(s8v*)&sV[p1 * 72 + cb + 8] = v1;

        __syncthreads();

        s8v a[2][2], bf[2][2];
#pragma unroll
        for (int mt = 0; mt < 2; ++mt) {
            const int p = wi * 32 + mt * 16 + lm;
#pragma unroll
            for (int ks = 0; ks < 2; ++ks)
                a[mt][ks] = *(const s8v*)&sV[p * 72 + ks * 32 + kg * 8];
        }
#pragma unroll
        for (int nt = 0; nt < 2; ++nt) {
            const int oc = wj * 32 + nt * 16 + lm;
#pragma unroll
            for (int ks = 0; ks < 2; ++ks)
                bf[nt][ks] = *(const s8v*)&sWd[oc * 72 + ks * 32 + kg * 8];
        }
#pragma unroll
        for (int mt = 0; mt < 2; ++mt)
#pragma unroll
            for (int nt = 0; nt < 2; ++nt)
#pragma unroll
                for (int ks = 0; ks < 2; ++ks)
                    acc[mt][nt] = __builtin_amdgcn_mfma_f32_16x16x32_bf16(
                        a[mt][ks], bf[nt][ks], acc[mt][nt], 0, 0, 0);
    }

#pragma unroll
    for (int mt = 0; mt < 2; ++mt)
#pragma unroll
        for (int nt = 0; nt < 2; ++nt) {
            const int oc = wj * 32 + nt * 16 + lm;
            const float bias = bdcn[oc];
#pragma unroll
            for (int r = 0; r < 4; ++r) {
                const int p = wi * 32 + mt * 16 + kg * 4 + r;
                const int y = y0 + (p >> 3), x = x0 + (p & 7);
                out[(((size_t)b * CC + oc) * HH + y) * WW + x] = acc[mt][nt][r] + bias;
            }
        }
}

extern "C" void kernel_launch(void* const* d_in, const int* in_sizes, int n_in,
                              void* d_out, int out_size, void* d_ws, size_t ws_size,
                              hipStream_t stream)
{
    const float* xvq  = (const float*)d_in[0];
    const float* xres = (const float*)d_in[1];
    const float* W1   = (const float*)d_in[2];
    const float* b1   = (const float*)d_in[3];
    const float* Woff = (const float*)d_in[4];
    const float* boff = (const float*)d_in[5];
    const float* Wmod = (const float*)d_in[6];
    const float* bmod = (const float*)d_in[7];
    const float* Wdcn = (const float*)d_in[8];
    const float* bdcn = (const float*)d_in[9];
    float* out = (float*)d_out;

    u16*  featb = (u16*)d_ws;                              // 8.39M u16
    float* om   = (float*)(featb + (size_t)BB * HH * WW * CC);  // 3.54M f32
    u16*  xin   = (u16*)(om + (size_t)BB * HH * WW * 27);  // 16.78M u16
    u16*  W1t   = xin + (size_t)BB * HH * WW * 128;        // 73728 u16
    u16*  Womt  = W1t + 9 * 64 * 128;                      // 18432 u16
    u16*  Wdt   = Womt + 9 * 32 * 64;                      // 36864 u16

    x2nhwc_kernel<<<dim3(HH, BB), 256, 0, stream>>>(xvq, xres, xin);
    w1trans_kernel<<<dim3(288), 256, 0, stream>>>(W1, W1t);
    womtrans_kernel<<<dim3(72), 256, 0, stream>>>(Woff, Wmod, Womt);
    wdtrans_kernel<<<dim3(144), 256, 0, stream>>>(Wdcn, Wdt);
    conv1_mfma_kernel<<<dim3(8, 8, 8), 256, 0, stream>>>(xin, W1t, b1, featb);
    offmod_mfma_kernel<<<dim3(8, 8, 8), 256, 0, stream>>>(featb, Womt, boff, bmod, om);
    dcn_mfma_kernel<<<dim3(16, 16, 8), 256, 0, stream>>>(featb, om, Wdt, bdcn, out);
}

// Round 5
// 211.674 us; speedup vs baseline: 5.7877x; 1.0554x over previous
//
#include <hip/hip_runtime.h>
#include <cmath>

#define BB 8
#define CC 64
#define HH 128
#define WW 128

typedef short s8v __attribute__((ext_vector_type(8)));      // raw 16B move
typedef float f4v __attribute__((ext_vector_type(4)));      // 4 fp32 acc
typedef _Float16 h8 __attribute__((ext_vector_type(8)));    // 8 f16 (4 VGPRs)
typedef unsigned short u16;
typedef u16 u4v __attribute__((ext_vector_type(4)));

__device__ __forceinline__ u16 f2h(float f) {
    _Float16 h = (_Float16)f;
    return __builtin_bit_cast(u16, h);
}
__device__ __forceinline__ _Float16 h_from_bits(u16 b) {
    return __builtin_bit_cast(_Float16, b);
}

// ---------------------------------------------------------------------------
// Kernel 0: NCHW fp32 (x_vq ++ x_res) -> NHWC f16 xin[B][H][W][128]
// float4 global reads, LDS transpose, ushort4 coalesced writes.
// ---------------------------------------------------------------------------
__global__ __launch_bounds__(256)
void x2nhwc_kernel(const float* __restrict__ xvq, const float* __restrict__ xres,
                   u16* __restrict__ xout)
{
    const int h = blockIdx.x;
    const int b = blockIdx.y;
    __shared__ u16 lds[128 * 132];

    for (int i = 0; i < 16; ++i) {
        const int idx = threadIdx.x + 256 * i;       // 4096 float4
        const int c = idx >> 5;
        const int w4 = (idx & 31) * 4;
        const float* src = (c < 64)
            ? &xvq[(((size_t)b * 64 + c) * HH + h) * WW]
            : &xres[(((size_t)b * 64 + (c - 64)) * HH + h) * WW];
        const float4 v = *(const float4*)(src + w4);
        lds[(w4 + 0) * 132 + c] = f2h(v.x);
        lds[(w4 + 1) * 132 + c] = f2h(v.y);
        lds[(w4 + 2) * 132 + c] = f2h(v.z);
        lds[(w4 + 3) * 132 + c] = f2h(v.w);
    }
    __syncthreads();
    u16* orow = xout + (((size_t)b * HH + h) * WW) * 128;
    for (int i = 0; i < 16; ++i) {
        const int idx = threadIdx.x + 256 * i;       // 4096 ushort4
        const int w = idx >> 5;
        const int q = idx & 31;
        *(u4v*)(orow + (size_t)w * 128 + q * 4) = *(const u4v*)&lds[w * 132 + q * 4];
    }
}

// ---------------------------------------------------------------------------
// Fused weight transforms (fp32 -> f16):
//  W1  [oc64][ic128][3][3] -> W1t  [tap9][oc64][ic128]     (73728)
//  Woff[18]/Wmod[9]        -> Womt [tap9][o32(27)][c64]    (18432)
//  Wdcn[oc][c][k]          -> Wdt  [k9][oc64][c64]         (36864)
// ---------------------------------------------------------------------------
__global__ void wfuse_kernel(const float* __restrict__ W1, const float* __restrict__ Woff,
                             const float* __restrict__ Wmod, const float* __restrict__ Wdcn,
                             u16* __restrict__ W1t, u16* __restrict__ Womt,
                             u16* __restrict__ Wdt)
{
    int idx = blockIdx.x * 256 + threadIdx.x;
    if (idx < 73728) {
        const int ic = idx & 127;
        const int oc = (idx >> 7) & 63;
        const int t  = idx >> 13;
        W1t[idx] = f2h(W1[((size_t)(oc * 128 + ic)) * 9 + t]);
        return;
    }
    idx -= 73728;
    if (idx < 18432) {
        const int c = idx & 63;
        const int o = (idx >> 6) & 31;
        const int t = idx >> 11;
        float v = 0.f;
        if (o < 18)      v = Woff[((size_t)(o * 64 + c)) * 9 + t];
        else if (o < 27) v = Wmod[((size_t)((o - 18) * 64 + c)) * 9 + t];
        Womt[idx] = f2h(v);
        return;
    }
    idx -= 18432;
    if (idx < 36864) {
        const int c  = idx & 63;
        const int oc = (idx >> 6) & 63;
        const int k  = idx >> 12;
        Wdt[idx] = f2h(Wdcn[((size_t)(oc * 64 + c)) * 9 + k]);
    }
}

// ---------------------------------------------------------------------------
// Kernel A: conv1 implicit-GEMM f16 MFMA. 16x16 px x 64 oc per block.
// K chunked by 32 ic; all 9 taps' weights for the chunk resident in LDS.
// feat out: f16 NHWC [B][H][W][64].
// ---------------------------------------------------------------------------
__global__ __launch_bounds__(256)
void conv1_mfma_kernel(const u16* __restrict__ xin, const u16* __restrict__ W1t,
                       const float* __restrict__ b1, u16* __restrict__ feath)
{
    __shared__ u16 sTile[324 * 36];   // [18x18][ic32 pad36] 23.3 KB
    __shared__ u16 sW[576 * 36];      // [tap*64+oc][ic32 pad36] 41.5 KB

    const int x0 = blockIdx.x * 16;
    const int y0 = blockIdx.y * 16;
    const int b  = blockIdx.z;
    const int tid = threadIdx.x;
    const int lane = tid & 63;
    const int wave = tid >> 6;
    const int lm = lane & 15;
    const int kg = lane >> 4;

    const u16* xb = xin + ((size_t)b * HH * WW) * 128;

    f4v acc[4][4];
#pragma unroll
    for (int i = 0; i < 4; ++i)
#pragma unroll
        for (int j = 0; j < 4; ++j) acc[i][j] = (f4v)0.f;

    for (int chunk = 0; chunk < 4; ++chunk) {
        const int c0 = chunk * 32;
        __syncthreads();
        for (int i = 0; i < 6; ++i) {
            const int idx = tid + 256 * i;
            if (idx < 1296) {
                const int pix = idx >> 2;
                const int q   = idx & 3;
                const int gy = y0 - 1 + pix / 18;
                const int gx = x0 - 1 + pix % 18;
                s8v v = (s8v)0;
                if ((unsigned)gy < HH && (unsigned)gx < WW)
                    v = *(const s8v*)(xb + ((size_t)(gy * WW + gx)) * 128 + c0 + q * 8);
                *(s8v*)&sTile[pix * 36 + q * 8] = v;
            }
        }
        for (int i = 0; i < 9; ++i) {
            const int idx = tid + 256 * i;
            const int row = idx >> 2;      // t*64 + oc
            const int q   = idx & 3;
            *(s8v*)&sW[row * 36 + q * 8] =
                *(const s8v*)(W1t + (size_t)row * 128 + c0 + q * 8);
        }
        __syncthreads();

#pragma unroll
        for (int t = 0; t < 9; ++t) {
            const int dy = t / 3, dx = t % 3;
            h8 a[4], bq[4];
#pragma unroll
            for (int mt = 0; mt < 4; ++mt) {
                const int p = wave * 64 + mt * 16 + lm;
                const int sidx = ((p >> 4) + dy) * 18 + (p & 15) + dx;
                a[mt] = *(const h8*)&sTile[sidx * 36 + kg * 8];
            }
#pragma unroll
            for (int nt = 0; nt < 4; ++nt) {
                const int oc = nt * 16 + lm;
                bq[nt] = *(const h8*)&sW[(t * 64 + oc) * 36 + kg * 8];
            }
#pragma unroll
            for (int mt = 0; mt < 4; ++mt)
#pragma unroll
                for (int nt = 0; nt < 4; ++nt)
                    acc[mt][nt] = __builtin_amdgcn_mfma_f32_16x16x32_f16(
                        a[mt], bq[nt], acc[mt][nt], 0, 0, 0);
        }
    }

#pragma unroll
    for (int nt = 0; nt < 4; ++nt) {
        const int oc = nt * 16 + lm;
        const float bias = b1[oc];
#pragma unroll
        for (int mt = 0; mt < 4; ++mt)
#pragma unroll
            for (int r = 0; r < 4; ++r) {
                const int p = wave * 64 + mt * 16 + kg * 4 + r;
                const int y = y0 + (p >> 4), x = x0 + (p & 15);
                feath[(((size_t)b * HH + y) * WW + x) * CC + oc] =
                    f2h(acc[mt][nt][r] + bias);
            }
    }
}

// ---------------------------------------------------------------------------
// Kernel B: offset+mod conv, 16x16 px x 32(27) out per block, f16 MFMA.
// ---------------------------------------------------------------------------
__global__ __launch_bounds__(256)
void offmod_mfma_kernel(const u16* __restrict__ feath, const u16* __restrict__ Womt,
                        const float* __restrict__ boff, const float* __restrict__ bmod,
                        float* __restrict__ om)
{
    __shared__ u16 sTile[324 * 36];   // [18x18][c32 pad36] 23.3 KB
    __shared__ u16 sWom[288 * 36];    // [t*32+o][c32 pad36] 20.7 KB

    const int x0 = blockIdx.x * 16;
    const int y0 = blockIdx.y * 16;
    const int b  = blockIdx.z;
    const int tid = threadIdx.x;
    const int lane = tid & 63;
    const int wave = tid >> 6;
    const int lm = lane & 15;
    const int kg = lane >> 4;

    const u16* fb = feath + ((size_t)b * HH * WW) * CC;

    f4v acc[4][2];
#pragma unroll
    for (int i = 0; i < 4; ++i)
#pragma unroll
        for (int j = 0; j < 2; ++j) acc[i][j] = (f4v)0.f;

    for (int chunk = 0; chunk < 2; ++chunk) {
        const int c0 = chunk * 32;
        __syncthreads();
        for (int i = 0; i < 6; ++i) {
            const int idx = tid + 256 * i;
            if (idx < 1296) {
                const int pix = idx >> 2;
                const int q   = idx & 3;
                const int gy = y0 - 1 + pix / 18;
                const int gx = x0 - 1 + pix % 18;
                s8v v = (s8v)0;
                if ((unsigned)gy < HH && (unsigned)gx < WW)
                    v = *(const s8v*)(fb + ((size_t)(gy * WW + gx)) * CC + c0 + q * 8);
                *(s8v*)&sTile[pix * 36 + q * 8] = v;
            }
        }
        for (int i = 0; i < 5; ++i) {
            const int idx = tid + 256 * i;
            if (idx < 1152) {
                const int row = idx >> 2;     // t*32 + o
                const int q   = idx & 3;
                *(s8v*)&sWom[row * 36 + q * 8] =
                    *(const s8v*)(Womt + (size_t)row * 64 + c0 + q * 8);
            }
        }
        __syncthreads();

#pragma unroll
        for (int t = 0; t < 9; ++t) {
            const int dy = t / 3, dx = t % 3;
            h8 a[4], bq[2];
#pragma unroll
            for (int mt = 0; mt < 4; ++mt) {
                const int p = wave * 64 + mt * 16 + lm;
                const int sidx = ((p >> 4) + dy) * 18 + (p & 15) + dx;
                a[mt] = *(const h8*)&sTile[sidx * 36 + kg * 8];
            }
#pragma unroll
            for (int nt = 0; nt < 2; ++nt) {
                const int o = nt * 16 + lm;
                bq[nt] = *(const h8*)&sWom[(t * 32 + o) * 36 + kg * 8];
            }
#pragma unroll
            for (int mt = 0; mt < 4; ++mt)
#pragma unroll
                for (int nt = 0; nt < 2; ++nt)
                    acc[mt][nt] = __builtin_amdgcn_mfma_f32_16x16x32_f16(
                        a[mt], bq[nt], acc[mt][nt], 0, 0, 0);
        }
    }

#pragma unroll
    for (int nt = 0; nt < 2; ++nt) {
        const int o = nt * 16 + lm;
        if (o >= 27) continue;
#pragma unroll
        for (int mt = 0; mt < 4; ++mt)
#pragma unroll
            for (int r = 0; r < 4; ++r) {
                const int p = wave * 64 + mt * 16 + kg * 4 + r;
                const int y = y0 + (p >> 4), x = x0 + (p & 15);
                float* op = om + (((size_t)b * HH + y) * WW + x) * 27;
                if (o < 18) op[o] = acc[mt][nt][r] + boff[o];
                else {
                    const float z = acc[mt][nt][r] + bmod[o - 18];
                    op[o] = 2.f / (1.f + expf(-z));
                }
            }
    }
}

// ---------------------------------------------------------------------------
// Kernel C: deformable sampling + modulated einsum, f16.
// Precompute phase builds per-(pixel,tap) records {4 clamped offsets,
// 4 f16 bilinear weights with mod folded in}; gather is pure v_pk_fma_f16
// (no unpack/pack); V stored f16 straight into LDS; per-tap 64x64x64 MFMA.
// ---------------------------------------------------------------------------
__global__ __launch_bounds__(256)
void dcn_mfma_kernel(const u16* __restrict__ feath, const float* __restrict__ om,
                     const u16* __restrict__ Wdt, const float* __restrict__ bdcn,
                     float* __restrict__ out)
{
    __shared__ u16 sV[64 * 72];       // [p][c64 pad72] 9.2 KB
    __shared__ u16 sWd[64 * 72];      // [oc][c64 pad72] 9.2 KB
    __shared__ float sOm[64 * 28];    // [p][27 pad28] 7.2 KB
    __shared__ int sOffs[576 * 4];    // [k*64+p][corner] 9.2 KB
    __shared__ u16 sWts[576 * 4];     // [k*64+p][corner] f16 w*mod 4.6 KB

    const int b  = blockIdx.z;
    const int x0 = blockIdx.x * 8;
    const int y0 = blockIdx.y * 8;
    const int tid = threadIdx.x;
    const int lane = tid & 63;
    const int wave = tid >> 6;
    const int wi = wave >> 1;
    const int wj = wave & 1;
    const int lm = lane & 15;
    const int kg = lane >> 4;

    for (int idx = tid; idx < 64 * 27; idx += 256) {
        const int p = idx / 27;
        const int j = idx - p * 27;
        const int y = y0 + (p >> 3), x = x0 + (p & 7);
        sOm[p * 28 + j] = om[(((size_t)b * HH + y) * WW + x) * 27 + j];
    }
    __syncthreads();

    // ---- precompute bilinear records (mod folded into corner weights) ----
    for (int idx = tid; idx < 576; idx += 256) {
        const int p = idx & 63, k = idx >> 6;
        const int yy = y0 + (p >> 3), xx = x0 + (p & 7);
        const float dy = sOm[p * 28 + 2 * k];
        const float dx = sOm[p * 28 + 2 * k + 1];
        const float m  = sOm[p * 28 + 18 + k];
        const float pyf = (float)(yy + (k / 3) - 1) + dy;
        const float pxf = (float)(xx + (k % 3) - 1) + dx;
        const float fy0 = floorf(pyf), fx0 = floorf(pxf);
        const float wy1 = pyf - fy0, wx1 = pxf - fx0;
        const int iy0 = (int)fy0, ix0 = (int)fx0;
        const float w[4] = { m * (1.f - wy1) * (1.f - wx1), m * (1.f - wy1) * wx1,
                             m * wy1 * (1.f - wx1),         m * wy1 * wx1 };
        const int ys[4] = { iy0, iy0, iy0 + 1, iy0 + 1 };
        const int xs[4] = { ix0, ix0 + 1, ix0, ix0 + 1 };
#pragma unroll
        for (int cn = 0; cn < 4; ++cn) {
            const bool valid = ((unsigned)ys[cn] < (unsigned)HH) &&
                               ((unsigned)xs[cn] < (unsigned)WW);
            sOffs[idx * 4 + cn] = valid ? (ys[cn] * WW + xs[cn]) * CC : 0;
            sWts[idx * 4 + cn]  = f2h(valid ? w[cn] : 0.f);
        }
    }

    // gather mapping: thread = (pixel p1, 16-ch group)
    const int p1 = tid >> 2;
    const int cb = (tid & 3) * 16;

    f4v acc[2][2];
#pragma unroll
    for (int i = 0; i < 2; ++i)
#pragma unroll
        for (int j = 0; j < 2; ++j) acc[i][j] = (f4v)0.f;

    const u16* fb = feath + ((size_t)b * HH * WW) * CC;

    for (int k = 0; k < 9; ++k) {
        __syncthreads();   // prev-tap LDS reads done; k=0: covers precompute

        // stage weights [oc][c] for tap k
        for (int i = 0; i < 2; ++i) {
            const int idx = tid + 256 * i;
            const int oc = idx >> 3;
            const int q  = idx & 7;
            *(s8v*)&sWd[oc * 72 + q * 8] =
                *(const s8v*)(Wdt + ((size_t)k * 64 + oc) * 64 + q * 8);
        }

        // ---- gather: V[p1][cb..cb+15] in pure packed-f16 ----
        const int rec = (k * 64 + p1) * 4;
        const int4 off4 = *(const int4*)&sOffs[rec];
        const u4v wt4   = *(const u4v*)&sWts[rec];

        h8 a0 = (h8)(_Float16)0.f, a1 = (h8)(_Float16)0.f;
        {
            const u16* cp = fb + off4.x + cb;
            const h8 w8 = (h8)h_from_bits(wt4.x);
            a0 += w8 * *(const h8*)(cp);
            a1 += w8 * *(const h8*)(cp + 8);
        }
        {
            const u16* cp = fb + off4.y + cb;
            const h8 w8 = (h8)h_from_bits(wt4.y);
            a0 += w8 * *(const h8*)(cp);
            a1 += w8 * *(const h8*)(cp + 8);
        }
        {
            const u16* cp = fb + off4.z + cb;
            const h8 w8 = (h8)h_from_bits(wt4.z);
            a0 += w8 * *(const h8*)(cp);
            a1 += w8 * *(const h8*)(cp + 8);
        }
        {
            const u16* cp = fb + off4.w + cb;
            const h8 w8 = (h8)h_from_bits(wt4.w);
            a0 += w8 * *(const h8*)(cp);
            a1 += w8 * *(const h8*)(cp + 8);
        }
        *(h8*)&sV[p1 * 72 + cb]     = a0;
        *(h8*)&sV[p1 * 72 + cb + 8] = a1;

        __syncthreads();

        // ---- GEMM: acc += V[64p][64c] * Wd[64c][64oc] ----
        h8 a[2][2], bf[2][2];
#pragma unroll
        for (int mt = 0; mt < 2; ++mt) {
            const int p = wi * 32 + mt * 16 + lm;
#pragma unroll
            for (int ks = 0; ks < 2; ++ks)
                a[mt][ks] = *(const h8*)&sV[p * 72 + ks * 32 + kg * 8];
        }
#pragma unroll
        for (int nt = 0; nt < 2; ++nt) {
            const int oc = wj * 32 + nt * 16 + lm;
#pragma unroll
            for (int ks = 0; ks < 2; ++ks)
                bf[nt][ks] = *(const h8*)&sWd[oc * 72 + ks * 32 + kg * 8];
        }
#pragma unroll
        for (int mt = 0; mt < 2; ++mt)
#pragma unroll
            for (int nt = 0; nt < 2; ++nt)
#pragma unroll
                for (int ks = 0; ks < 2; ++ks)
                    acc[mt][nt] = __builtin_amdgcn_mfma_f32_16x16x32_f16(
                        a[mt][ks], bf[nt][ks], acc[mt][nt], 0, 0, 0);
    }

    // epilogue: NCHW fp32
#pragma unroll
    for (int mt = 0; mt < 2; ++mt)
#pragma unroll
        for (int nt = 0; nt < 2; ++nt) {
            const int oc = wj * 32 + nt * 16 + lm;
            const float bias = bdcn[oc];
#pragma unroll
            for (int r = 0; r < 4; ++r) {
                const int p = wi * 32 + mt * 16 + kg * 4 + r;
                const int y = y0 + (p >> 3), x = x0 + (p & 7);
                out[(((size_t)b * CC + oc) * HH + y) * WW + x] = acc[mt][nt][r] + bias;
            }
        }
}

extern "C" void kernel_launch(void* const* d_in, const int* in_sizes, int n_in,
                              void* d_out, int out_size, void* d_ws, size_t ws_size,
                              hipStream_t stream)
{
    const float* xvq  = (const float*)d_in[0];
    const float* xres = (const float*)d_in[1];
    const float* W1   = (const float*)d_in[2];
    const float* b1   = (const float*)d_in[3];
    const float* Woff = (const float*)d_in[4];
    const float* boff = (const float*)d_in[5];
    const float* Wmod = (const float*)d_in[6];
    const float* bmod = (const float*)d_in[7];
    const float* Wdcn = (const float*)d_in[8];
    const float* bdcn = (const float*)d_in[9];
    float* out = (float*)d_out;

    u16*  feath = (u16*)d_ws;                              // 8.39M u16
    float* om   = (float*)(feath + (size_t)BB * HH * WW * CC);  // 3.54M f32
    u16*  xin   = (u16*)(om + (size_t)BB * HH * WW * 27);  // 16.78M u16
    u16*  W1t   = xin + (size_t)BB * HH * WW * 128;        // 73728 u16
    u16*  Womt  = W1t + 9 * 64 * 128;                      // 18432 u16
    u16*  Wdt   = Womt + 9 * 32 * 64;                      // 36864 u16

    x2nhwc_kernel<<<dim3(HH, BB), 256, 0, stream>>>(xvq, xres, xin);
    wfuse_kernel<<<dim3(504), 256, 0, stream>>>(W1, Woff, Wmod, Wdcn, W1t, Womt, Wdt);
    conv1_mfma_kernel<<<dim3(8, 8, 8), 256, 0, stream>>>(xin, W1t, b1, feath);
    offmod_mfma_kernel<<<dim3(8, 8, 8), 256, 0, stream>>>(feath, Womt, boff, bmod, om);
    dcn_mfma_kernel<<<dim3(16, 16, 8), 256, 0, stream>>>(feath, om, Wdt, bdcn, out);
}